// Round 3
// baseline (166.680 us; speedup 1.0000x reference)
//
#include <hip/hip_runtime.h>

#define THREADS 256

typedef __attribute__((ext_vector_type(8))) short bf16x8;
typedef __attribute__((ext_vector_type(4))) float f32x4;

// fp32 -> bf16 round-to-nearest-even
__device__ inline unsigned short f2bf(float f) {
    union { float f; unsigned int u; } v; v.f = f;
    unsigned int r = v.u + 0x7fffu + ((v.u >> 16) & 1u);
    return (unsigned short)(r >> 16);
}
// pack two f32 -> (hi<<16)|lo bf16 pair
__device__ inline unsigned int pack2(float lo, float hi) {
    return (unsigned int)f2bf(lo) | ((unsigned int)f2bf(hi) << 16);
}
__device__ inline float bflo(unsigned int u) {
    union { unsigned int u; float f; } v; v.u = u << 16; return v.f;
}
__device__ inline float bfhi(unsigned int u) {
    union { unsigned int u; float f; } v; v.u = u & 0xffff0000u; return v.f;
}

// ---------------------------------------------------------------------------
// Kernel A2: in-side contraction, 2 rows/block. x[N,4096] -> u3b[N,512] bf16.
// Blocks < 256 also convert core fp32 -> coreb bf16 (1 float4/thread).
//   u1[d,e,n6] = sum_f x[d,e,f] * f5[f,n6]
//   u2[d,m,n6] = sum_e u1[d,e,n6] * f4[e,m]
//   u3[l,m,n6] = sum_d u2[d,m,n6] * f3[d,l]
// ---------------------------------------------------------------------------
__global__ __launch_bounds__(THREADS) void k_in_contract2(
    const float* __restrict__ x,
    const float* __restrict__ f3, const float* __restrict__ f4,
    const float* __restrict__ f5, const float* __restrict__ core,
    unsigned short* __restrict__ u3b, unsigned short* __restrict__ coreb,
    int N)
{
    const int n0 = blockIdx.x * 2;
    const int t  = threadIdx.x;

    __shared__ float fs[256];          // f3 [0..128) | f4 [128..256)
    __shared__ float u1s[2][256 * 9];  // [row][de][n6], pad 9
    __shared__ float u2s[2][128 * 9];  // [row][d*8+m][n6], pad 9

    if (t < 128) { fs[t] = f3[t]; fs[128 + t] = f4[t]; }

    // side-job: core fp32 -> bf16 (blocks 0..255, 1 float4 per thread)
    if (blockIdx.x < 256) {
        const int i = blockIdx.x * THREADS + t;   // float4 id, 0..65535
        float4 c = ((const float4*)core)[i];
        ushort4 o;
        o.x = f2bf(c.x); o.y = f2bf(c.y); o.z = f2bf(c.z); o.w = f2bf(c.w);
        ((ushort4*)coreb)[i] = o;
    }

    // x chunks for both rows: thread t owns de = t (16 consecutive floats)
    float xv[2][16];
    #pragma unroll
    for (int rr = 0; rr < 2; ++rr) {
        const float4* xr = (const float4*)(x + (size_t)(n0 + rr) * 4096 + t * 16);
        float4 a0 = xr[0], a1 = xr[1], a2 = xr[2], a3 = xr[3];
        xv[rr][0]=a0.x;  xv[rr][1]=a0.y;  xv[rr][2]=a0.z;  xv[rr][3]=a0.w;
        xv[rr][4]=a1.x;  xv[rr][5]=a1.y;  xv[rr][6]=a1.z;  xv[rr][7]=a1.w;
        xv[rr][8]=a2.x;  xv[rr][9]=a2.y;  xv[rr][10]=a2.z; xv[rr][11]=a2.w;
        xv[rr][12]=a3.x; xv[rr][13]=a3.y; xv[rr][14]=a3.z; xv[rr][15]=a3.w;
    }

    // u1: f5 values shared across both rows (lane-uniform -> scalar loads)
    float acc8[2][8];
    #pragma unroll
    for (int q = 0; q < 8; ++q) { acc8[0][q] = 0.f; acc8[1][q] = 0.f; }
    #pragma unroll
    for (int f = 0; f < 16; ++f) {
        #pragma unroll
        for (int n6 = 0; n6 < 8; ++n6) {
            const float w = f5[f*8 + n6];
            acc8[0][n6] = fmaf(xv[0][f], w, acc8[0][n6]);
            acc8[1][n6] = fmaf(xv[1][f], w, acc8[1][n6]);
        }
    }
    __syncthreads();   // fs ready
    #pragma unroll
    for (int n6 = 0; n6 < 8; ++n6) {
        u1s[0][t*9 + n6] = acc8[0][n6];
        u1s[1][t*9 + n6] = acc8[1][n6];
    }
    __syncthreads();

    // u2: thread -> (d = t>>4, m = (t>>1)&7, h = t&1), n6 = 4h..4h+3
    {
        const int d = t >> 4, m = (t >> 1) & 7, h = t & 1;
        float fr[16];
        #pragma unroll
        for (int e = 0; e < 16; ++e) fr[e] = fs[128 + e*8 + m];
        float a4[2][4] = {};
        #pragma unroll
        for (int e = 0; e < 16; ++e) {
            const int base = (d*16 + e)*9 + h*4;
            #pragma unroll
            for (int q = 0; q < 4; ++q) {
                a4[0][q] = fmaf(u1s[0][base + q], fr[e], a4[0][q]);
                a4[1][q] = fmaf(u1s[1][base + q], fr[e], a4[1][q]);
            }
        }
        #pragma unroll
        for (int q = 0; q < 4; ++q) {
            u2s[0][(d*8 + m)*9 + h*4 + q] = a4[0][q];
            u2s[1][(d*8 + m)*9 + h*4 + q] = a4[1][q];
        }
    }
    __syncthreads();

    // u3: thread -> (l = t>>5, m = (t>>2)&7, h = t&3); output offset 2t per row
    {
        const int l = t >> 5, m = (t >> 2) & 7, h = t & 3;
        float fr[16];
        #pragma unroll
        for (int d = 0; d < 16; ++d) fr[d] = fs[d*8 + l];
        float a2[2][2] = {};
        #pragma unroll
        for (int d = 0; d < 16; ++d) {
            const int base = (d*8 + m)*9 + h*2;
            a2[0][0] = fmaf(u2s[0][base],     fr[d], a2[0][0]);
            a2[0][1] = fmaf(u2s[0][base + 1], fr[d], a2[0][1]);
            a2[1][0] = fmaf(u2s[1][base],     fr[d], a2[1][0]);
            a2[1][1] = fmaf(u2s[1][base + 1], fr[d], a2[1][1]);
        }
        ((unsigned int*)u3b)[(size_t)(n0+0) * 256 + t] = pack2(a2[0][0], a2[0][1]);
        ((unsigned int*)u3b)[(size_t)(n0+1) * 256 + t] = pack2(a2[1][0], a2[1][1]);
    }
}

// ---------------------------------------------------------------------------
// Kernel K2: fused core-GEMM (MFMA, no LDS staging for inputs) + out-expand.
// 8 rows/block, 256 threads (4 waves), grid N/8 = 512.
//  GEMM: wave w covers cols [w*128, w*128+128): 8 tiles 16x16, K=512.
//        A-frag row = r0 + (lane&7)  (rows 8..15 duplicate, discarded)
//  v (fp32) -> LDS, then w1 = f0-contract, w2 = f1-contract (bf16-packed LDS),
//  y = f2-contract + bias, coalesced dwordx4 stores (addr = 4t + 1024g).
// LDS strides chosen for <=2-way conflicts on the hot reads:
//  vs row 520 dw; w1 a-stride 33 dw; w2 a-stride 5 / b-stride 81 dw (16 banks).
// ---------------------------------------------------------------------------
__global__ __launch_bounds__(THREADS) void k_gemm_expand(
    const unsigned short* __restrict__ u3b,
    const unsigned short* __restrict__ coreb,
    const float* __restrict__ f0, const float* __restrict__ f1,
    const float* __restrict__ f2, const float* __restrict__ bias,
    float* __restrict__ y, int N)
{
    __shared__ float        vsS[8 * 520];   // v fp32 [8 rows][512]
    __shared__ unsigned int w1S[8 * 528];   // w1 bf16-pairs [r][a*33 + jk/2]
    __shared__ unsigned int w2S[8 * 1300];  // w2 bf16-pairs [r][a*5 + b*81 + k/2]
    __shared__ float        fsS[256];       // f0 [0..128) | f1 [128..256)

    const int t  = threadIdx.x;
    const int r0 = blockIdx.x * 8;

    fsS[t] = (t < 128) ? f0[t] : f1[t - 128];

    // ---- GEMM phase: v[r][p] = sum_q u3[r0+r][q] * core[p][q] ----
    {
        const int lane = t & 63, w = t >> 6;
        const int lr = lane & 15, lq = lane >> 4;
        const unsigned short* ap = u3b + (size_t)(r0 + (lr & 7)) * 512 + lq * 8;
        const unsigned short* bp = coreb + (size_t)(w * 128 + lr) * 512 + lq * 8;

        f32x4 acc[8];
        #pragma unroll
        for (int c = 0; c < 8; ++c) acc[c] = (f32x4){0.f, 0.f, 0.f, 0.f};

        #pragma unroll
        for (int k0 = 0; k0 < 512; k0 += 32) {
            bf16x8 a = *(const bf16x8*)(ap + k0);
            #pragma unroll
            for (int c = 0; c < 8; ++c) {
                bf16x8 b = *(const bf16x8*)(bp + c * 8192 + k0);  // c*16*512
                acc[c] = __builtin_amdgcn_mfma_f32_16x16x32_bf16(a, b, acc[c], 0, 0, 0);
            }
        }
        // C/D: row(M) = lq*4+reg, col(N) = lane&15.  Valid rows: m < 8.
        if (lq < 2) {
            #pragma unroll
            for (int c = 0; c < 8; ++c)
                #pragma unroll
                for (int q = 0; q < 4; ++q)
                    vsS[(lq*4 + q)*520 + w*128 + c*16 + lr] = acc[c][q];
        }
    }
    __syncthreads();

    // ---- w1[r][a][jk] = sum_i f0[a,i] * v[r][i*64 + jk] ----
    {
        const int r = t >> 5, a = (t >> 1) & 15, h = t & 1;
        const float* vrow = vsS + r*520 + h*32;
        float fa[8];
        #pragma unroll
        for (int i = 0; i < 8; ++i) fa[i] = fsS[a*8 + i];
        #pragma unroll
        for (int q2 = 0; q2 < 16; ++q2) {
            float s0 = 0.f, s1 = 0.f;
            #pragma unroll
            for (int i = 0; i < 8; ++i) {
                s0 = fmaf(fa[i], vrow[i*64 + 2*q2],     s0);
                s1 = fmaf(fa[i], vrow[i*64 + 2*q2 + 1], s1);
            }
            w1S[r*528 + a*33 + h*16 + q2] = pack2(s0, s1);
        }
    }
    __syncthreads();

    // ---- w2[r][a][b][k] = sum_j f1[b,j] * w1[r][a][j*8+k] ----
    {
        const int r = t >> 5, a = (t >> 1) & 15, h = t & 1;
        const unsigned int* w1row = w1S + r*528 + a*33;
        float acc[8][8] = {};
        #pragma unroll
        for (int j = 0; j < 8; ++j) {
            float wj[8];
            #pragma unroll
            for (int k2 = 0; k2 < 4; ++k2) {
                const unsigned int u = w1row[j*4 + k2];
                wj[2*k2]     = bflo(u);
                wj[2*k2 + 1] = bfhi(u);
            }
            #pragma unroll
            for (int bi = 0; bi < 8; ++bi) {
                const float fb = fsS[128 + (h*8 + bi)*8 + j];
                #pragma unroll
                for (int k = 0; k < 8; ++k)
                    acc[bi][k] = fmaf(fb, wj[k], acc[bi][k]);
            }
        }
        #pragma unroll
        for (int bi = 0; bi < 8; ++bi) {
            const int b = h*8 + bi;
            #pragma unroll
            for (int k2 = 0; k2 < 4; ++k2)
                w2S[r*1300 + a*5 + b*81 + k2] = pack2(acc[bi][2*k2], acc[bi][2*k2+1]);
        }
    }
    __syncthreads();

    // ---- y[r][a,b,c] = bias[abc] + sum_k f2[c,k] * w2[r][a][b][k] ----
    {
        const int cq = t & 3, s = t >> 2;   // c-quad, ab-group
        float f2r[4][8];
        #pragma unroll
        for (int cc = 0; cc < 4; ++cc)
            #pragma unroll
            for (int k = 0; k < 8; ++k)
                f2r[cc][k] = f2[(cq*4 + cc)*8 + k];
        float4 br[4];
        #pragma unroll
        for (int g = 0; g < 4; ++g)
            br[g] = *(const float4*)(bias + (size_t)(s + 64*g)*16 + cq*4);

        #pragma unroll
        for (int r = 0; r < 8; ++r) {
            float4* orow = (float4*)(y + (size_t)(r0 + r) * 4096);
            #pragma unroll
            for (int g = 0; g < 4; ++g) {
                const int ab = s + 64*g, a = ab >> 4, b = ab & 15;
                const unsigned int* w2row = w2S + r*1300 + a*5 + b*81;
                float wf[8];
                #pragma unroll
                for (int k2 = 0; k2 < 4; ++k2) {
                    const unsigned int u = w2row[k2];
                    wf[2*k2]     = bflo(u);
                    wf[2*k2 + 1] = bfhi(u);
                }
                float4 o = br[g];
                #pragma unroll
                for (int k = 0; k < 8; ++k) {
                    o.x = fmaf(f2r[0][k], wf[k], o.x);
                    o.y = fmaf(f2r[1][k], wf[k], o.y);
                    o.z = fmaf(f2r[2][k], wf[k], o.z);
                    o.w = fmaf(f2r[3][k], wf[k], o.w);
                }
                orow[t + 256*g] = o;   // float4 idx = ab*4+cq = 4t/4... = t+256g
            }
        }
    }
}

// ---------------------------------------------------------------------------
extern "C" void kernel_launch(void* const* d_in, const int* in_sizes, int n_in,
                              void* d_out, int out_size, void* d_ws, size_t ws_size,
                              hipStream_t stream)
{
    const float* x    = (const float*)d_in[0];
    const float* core = (const float*)d_in[1];
    const float* f0   = (const float*)d_in[2];
    const float* f1   = (const float*)d_in[3];
    const float* f2   = (const float*)d_in[4];
    const float* f3   = (const float*)d_in[5];
    const float* f4   = (const float*)d_in[6];
    const float* f5   = (const float*)d_in[7];
    const float* bias = (const float*)d_in[8];
    float* y = (float*)d_out;

    const int N = in_sizes[0] / 4096;

    // workspace: u3b bf16 [N,512] (4MB) | coreb bf16 [512,512] (0.5MB)
    unsigned short* u3b   = (unsigned short*)d_ws;
    unsigned short* coreb = u3b + (size_t)N * 512;

    k_in_contract2<<<N / 2, THREADS, 0, stream>>>(x, f3, f4, f5, core, u3b, coreb, N);
    k_gemm_expand<<<N / 8, THREADS, 0, stream>>>(u3b, coreb, f0, f1, f2, bias, y, N);
}